// Round 8
// baseline (333.628 us; speedup 1.0000x reference)
//
#include <hip/hip_runtime.h>
#include <hip/hip_bf16.h>

#define T_NODES 32768
#define NPG 1024
#define BGR 32
#define D 64
#define FIN 8

// ---- DPP add helpers (VALU pipe, no LDS traffic)
template<int CTRL, int RM, int BM>
__device__ __forceinline__ float dpp_add(float x){
    int y = __builtin_amdgcn_update_dpp(0, __float_as_int(x), CTRL, RM, BM, false);
    return x + __int_as_float(y);
}
// full-wave sum, result in lane 63 (rocPRIM pattern)
__device__ __forceinline__ float wave_sum63(float x){
    x = dpp_add<0x111,0xf,0xf>(x);   // row_shr:1
    x = dpp_add<0x112,0xf,0xf>(x);   // row_shr:2
    x = dpp_add<0x114,0xf,0xe>(x);   // row_shr:4
    x = dpp_add<0x118,0xf,0xc>(x);   // row_shr:8
    x = dpp_add<0x142,0xa,0xf>(x);   // row_bcast:15
    x = dpp_add<0x143,0xc,0xf>(x);   // row_bcast:31
    return x;
}
__device__ __forceinline__ float wave_sum_bcast(float x){
    return __int_as_float(__builtin_amdgcn_readlane(__float_as_int(wave_sum63(x)), 63));
}
// 16-lane-row sum via rotate-add: EVERY lane of the row ends with the row total
__device__ __forceinline__ float row_ror_add(float x){
    x = dpp_add<0x121,0xf,0xf>(x);   // row_ror:1
    x = dpp_add<0x122,0xf,0xf>(x);   // row_ror:2
    x = dpp_add<0x124,0xf,0xf>(x);   // row_ror:4
    x = dpp_add<0x128,0xf,0xf>(x);   // row_ror:8
    return x;
}

// XCD-aware swizzle: XCD x owns graphs 4x..4x+3 (pure permutation; perf-only).

__global__ void count_kernel(const int* __restrict__ dst, int* __restrict__ counts, int E){
    int i = blockIdx.x*blockDim.x + threadIdx.x;
    if (i < E) atomicAdd(&counts[dst[i]], 1);
}

// one block, 1024 threads, T = 32768 = 1024*32
__global__ void scan_kernel(const int* __restrict__ counts, int* __restrict__ indptr,
                            int* __restrict__ cursor, int T){
    __shared__ int bufA[1024];
    __shared__ int bufB[1024];
    int tid = threadIdx.x;
    int base = tid * 32;
    int local[32];
    int s = 0;
    #pragma unroll
    for (int i = 0; i < 32; i++){ local[i] = counts[base+i]; s += local[i]; }
    bufA[tid] = s;
    __syncthreads();
    int* src = bufA; int* dst = bufB;
    for (int off = 1; off < 1024; off <<= 1){
        int v = src[tid];
        if (tid >= off) v += src[tid - off];
        dst[tid] = v;
        __syncthreads();
        int* t = src; src = dst; dst = t;
    }
    int excl = src[tid] - s;
    int run = excl;
    #pragma unroll
    for (int i = 0; i < 32; i++){
        indptr[base+i] = run;
        cursor[base+i] = run;
        run += local[i];
    }
    if (tid == 1023) indptr[T] = run;
}

__global__ void scatter_kernel(const int* __restrict__ src, const int* __restrict__ dst,
                               int* __restrict__ cursor, int* __restrict__ col, int E){
    int i = blockIdx.x*blockDim.x + threadIdx.x;
    if (i < E){
        int d = dst[i];
        int pos = atomicAdd(&cursor[d], 1);
        col[pos] = src[i];
    }
}

// ---------------- layer 0 linear + zero-init fused ----------------
__global__ void lin0_kernel(const float* __restrict__ x, const float* __restrict__ Wl0,
                            const float* __restrict__ Wr0,
                            float* __restrict__ xl, float* __restrict__ xr,
                            int* __restrict__ counts, float* __restrict__ muAcc){
    __shared__ float wl[D][FIN+1];
    __shared__ float wr[D][FIN+1];
    __shared__ float xs[32][FIN];
    int tid = threadIdx.x;
    int blk = blockIdx.x;
    int gidx = blk*256 + tid;                         // 262144 threads total
    if (gidx < T_NODES) counts[gidx] = 0;             // fused zero_kernel
    if (gidx < BGR*D)   muAcc[gidx] = 0.f;
    int rowBase = (blk & 7)*4096 + (blk >> 3)*32;     // XCD swizzle
    for (int i = tid; i < D*FIN; i += 256){
        wl[i>>3][i&7] = Wl0[i];
        wr[i>>3][i&7] = Wr0[i];
    }
    xs[tid>>3][tid&7] = x[rowBase*FIN + tid];         // coalesced 1 KB stage
    __syncthreads();
    int wave = tid >> 6, lane = tid & 63;
    int rb = rowBase + wave*8;
    #pragma unroll
    for (int r = 0; r < 8; r++){
        float al = 0.f, ar = 0.f;
        int lr = wave*8 + r;
        #pragma unroll
        for (int k = 0; k < FIN; k++){
            float xv = xs[lr][k];
            al = fmaf(xv, wl[lane][k], al);
            ar = fmaf(xv, wr[lane][k], ar);
        }
        xl[(rb+r)*D + lane] = al;
        xr[(rb+r)*D + lane] = ar;
    }
}

// ---------------- layers 1-4: LDS-tiled outer-product GEMM ----------------
__global__ __launch_bounds__(256) void lin_kernel(const float* __restrict__ h,
                           const float* __restrict__ Wl, const float* __restrict__ Wr,
                           float* __restrict__ xl, float* __restrict__ xr){
    __shared__ __align__(16) float hs[D][68];
    __shared__ __align__(16) float wls[D][68];
    __shared__ __align__(16) float wrs[D][68];
    int tid = threadIdx.x;
    int blk = blockIdx.x;
    int rowBase = (blk & 7)*4096 + (blk >> 3)*64;     // XCD swizzle
    for (int i = tid; i < D*D; i += 256){
        int r = i >> 6, c = i & 63;
        hs[r][c]  = fmaxf(h[rowBase*D + i], 0.f);     // relu at stage
        wls[r][c] = Wl[i];
        wrs[r][c] = Wr[i];
    }
    __syncthreads();
    int ty = tid >> 4, tx = tid & 15;
    int r0 = ty * 4;
    float accl[4][4], accr[4][4];
    #pragma unroll
    for (int i = 0; i < 4; i++)
        #pragma unroll
        for (int j = 0; j < 4; j++){ accl[i][j] = 0.f; accr[i][j] = 0.f; }
    for (int k = 0; k < D; k += 4){
        float4 hv[4], wlv[4], wrv[4];
        #pragma unroll
        for (int i = 0; i < 4; i++){
            hv[i]  = *(const float4*)&hs[r0+i][k];
            wlv[i] = *(const float4*)&wls[tx + 16*i][k];
            wrv[i] = *(const float4*)&wrs[tx + 16*i][k];
        }
        #pragma unroll
        for (int i = 0; i < 4; i++){
            #pragma unroll
            for (int j = 0; j < 4; j++){
                accl[i][j] += hv[i].x*wlv[j].x + hv[i].y*wlv[j].y
                            + hv[i].z*wlv[j].z + hv[i].w*wlv[j].w;
                accr[i][j] += hv[i].x*wrv[j].x + hv[i].y*wrv[j].y
                            + hv[i].z*wrv[j].z + hv[i].w*wrv[j].w;
            }
        }
    }
    #pragma unroll
    for (int i = 0; i < 4; i++){
        int row = (rowBase + r0 + i) * D;
        #pragma unroll
        for (int j = 0; j < 4; j++){
            xl[row + tx + 16*j] = accl[i][j];
            xr[row + tx + 16*j] = accr[i][j];
        }
    }
}

// ---------------- GATv2 edge softmax + aggregation ----------------
// One wave per dst node; one 16-lane ROW per edge, lane covers 4 features.
// Fast path (nEdge<=32, >99.9% of nodes): 8 independent gathers issued as one
// burst (max MLP), then straight-line compute. No serial pass structure.
__global__ __launch_bounds__(256) void edge_kernel(const float* __restrict__ xl,
                            const float* __restrict__ xr,
                            const float* __restrict__ att, const float* __restrict__ bias,
                            const int* __restrict__ indptr, const int* __restrict__ col,
                            float* __restrict__ hout, float* __restrict__ muAcc, int E){
    int wave = threadIdx.x >> 6, lane = threadIdx.x & 63;
    int blk = blockIdx.x;
    int t = (blk & 7)*4096 + (blk >> 3)*4 + wave;     // XCD swizzle
    int row = lane >> 4;
    int sub4 = (lane & 15) << 2;                 // this lane's 4 feature dims
    float4 a4  = *(const float4*)&att[sub4];
    float4 xr4 = *(const float4*)&xr[t*D + sub4];
    int beg = indptr[t], end = indptr[t+1];
    int deg = end - beg;
    int idx = beg + lane; idx = idx < E ? idx : E - 1;
    int sAll = (lane < deg) ? col[idx] : t;      // lanes >= deg carry the self-loop src
    int nEdge = deg + 1;                          // + self loop
    float4 acc = make_float4(0.f, 0.f, 0.f, 0.f);
    float l = 0.f;
    if (nEdge <= 32){
        float4 xv[8];
        #pragma unroll
        for (int i = 0; i < 8; i++){              // burst: 8 loads in flight
            int j = i*4 + row;
            int jc = (j < nEdge) ? j : (nEdge-1);
            int s = __shfl(sAll, jc, 64);
            xv[i] = *(const float4*)&xl[((size_t)(unsigned)s << 6) + sub4];
        }
        #pragma unroll
        for (int i = 0; i < 8; i++){
            float v, e;
            v = xv[i].x + xr4.x; v = fmaxf(v, 0.2f*v); e = v*a4.x;
            v = xv[i].y + xr4.y; v = fmaxf(v, 0.2f*v); e = fmaf(v, a4.y, e);
            v = xv[i].z + xr4.z; v = fmaxf(v, 0.2f*v); e = fmaf(v, a4.z, e);
            v = xv[i].w + xr4.w; v = fmaxf(v, 0.2f*v); e = fmaf(v, a4.w, e);
            e = row_ror_add(e);                   // every lane in row has edge score
            float q = (i*4 + row < nEdge) ? __expf(e) : 0.f;
            l += q;
            acc.x = fmaf(q, xv[i].x, acc.x);
            acc.y = fmaf(q, xv[i].y, acc.y);
            acc.z = fmaf(q, xv[i].z, acc.z);
            acc.w = fmaf(q, xv[i].w, acc.w);
        }
    } else {                                      // rare (~0.02% of nodes)
        for (int j0 = 0; j0 < nEdge; j0 += 4){
            int j = j0 + row;
            int jc = (j < nEdge) ? j : (nEdge-1);
            int s;
            if (jc < 64) s = __shfl(sAll, jc, 64);
            else         s = (jc < deg) ? col[beg + jc] : t;
            float4 xv = *(const float4*)&xl[((size_t)(unsigned)s << 6) + sub4];
            float v, e;
            v = xv.x + xr4.x; v = fmaxf(v, 0.2f*v); e = v*a4.x;
            v = xv.y + xr4.y; v = fmaxf(v, 0.2f*v); e = fmaf(v, a4.y, e);
            v = xv.z + xr4.z; v = fmaxf(v, 0.2f*v); e = fmaf(v, a4.z, e);
            v = xv.w + xr4.w; v = fmaxf(v, 0.2f*v); e = fmaf(v, a4.w, e);
            e = row_ror_add(e);
            float q = (j < nEdge) ? __expf(e) : 0.f;
            l += q;
            acc.x = fmaf(q, xv.x, acc.x);
            acc.y = fmaf(q, xv.y, acc.y);
            acc.z = fmaf(q, xv.z, acc.z);
            acc.w = fmaf(q, xv.w, acc.w);
        }
    }
    // combine the 4 rows' disjoint edge subsets (xor over bits 4,5)
    #pragma unroll
    for (int o = 16; o < 64; o <<= 1){
        acc.x += __shfl_xor(acc.x, o, 64);
        acc.y += __shfl_xor(acc.y, o, 64);
        acc.z += __shfl_xor(acc.z, o, 64);
        acc.w += __shfl_xor(acc.w, o, 64);
        l     += __shfl_xor(l,     o, 64);
    }
    float4 b4 = *(const float4*)&bias[sub4];
    float4 hv;
    hv.x = acc.x / l + b4.x;
    hv.y = acc.y / l + b4.y;
    hv.z = acc.z / l + b4.z;
    hv.w = acc.w / l + b4.w;
    if (row == 0)
        *(float4*)&hout[t*D + sub4] = hv;        // 16 lanes x 16B = 256B store
    if (muAcc){                                   // last layer: graph-mean partial
        __shared__ float red[4][D];
        if (row == 0) *(float4*)&red[wave][sub4] = hv;
        __syncthreads();
        if (wave == 0){
            float s = red[0][lane] + red[1][lane] + red[2][lane] + red[3][lane];
            atomicAdd(&muAcc[(t >> 10)*D + lane], s);
        }
    }
}

// ---------------- per-node head with inlined per-graph pool ----------------
// Each block redundantly computes its graph's (Pg,Qg) from muAcc (cheap: 4K FMA),
// then does the 64-node tile GEMM for logits + masked q. Saves pool2 dispatch.
__global__ __launch_bounds__(256) void final_kernel(const float* __restrict__ h,
                             const float* __restrict__ muAcc,
                             const float* __restrict__ t6w, const float* __restrict__ t6b,
                             const float* __restrict__ t7w, const float* __restrict__ t7b,
                             const float* __restrict__ t5pw, const float* __restrict__ t5pb,
                             const float* __restrict__ t5vw, const float* __restrict__ t5vb,
                             const float* __restrict__ pw, const float* __restrict__ pb,
                             const int* __restrict__ reachable,
                             float* __restrict__ out_logits, float* __restrict__ qbuf){
    __shared__ __align__(16) float hs[D][68];
    __shared__ __align__(16) float ws[D][68];
    __shared__ float ppar[D][17];
    __shared__ float qpar[D][17];
    __shared__ float PgQg[2];
    int tid = threadIdx.x;
    int blk = blockIdx.x;
    int rowBase = (blk & 7)*4096 + (blk >> 3)*64;     // XCD swizzle
    int b = rowBase >> 10;                            // this block's graph
    // phase 0: Pg/Qg for graph b (t6w staged in ws; mu staged in hs row 0)
    for (int i = tid; i < D*D; i += 256) ws[i>>6][i&63] = t6w[i];
    if (tid < D) hs[0][tid] = muAcc[b*D + tid] * (1.f/NPG);
    __syncthreads();
    if (tid < D){
        int d = tid;
        float g = t6b[d];
        #pragma unroll
        for (int k = 0; k < D; k++) g = fmaf(hs[0][k], ws[d][k], g);
        g = fmaxf(g, 0.f);
        float pp = wave_sum_bcast(g * t5pw[d]);       // first half of [1,128]
        float qq = wave_sum_bcast(g * t5vw[d]);
        if (d == 0){ PgQg[0] = pp; PgQg[1] = qq; }
    }
    __syncthreads();
    // phase 1: stage h tile + t7w (overwrites phase-0 LDS)
    for (int i = tid; i < D*D; i += 256){
        int r = i >> 6, c = i & 63;
        hs[r][c] = h[rowBase*D + i];                  // NO relu on h here
        ws[r][c] = t7w[i];
    }
    __syncthreads();
    int ty = tid >> 4, tx = tid & 15;
    int r0 = ty * 4;
    float acc[4][4];
    #pragma unroll
    for (int i = 0; i < 4; i++)
        #pragma unroll
        for (int j = 0; j < 4; j++) acc[i][j] = 0.f;
    for (int k = 0; k < D; k += 4){
        float4 hv[4], wv[4];
        #pragma unroll
        for (int i = 0; i < 4; i++){
            hv[i] = *(const float4*)&hs[r0+i][k];
            wv[i] = *(const float4*)&ws[tx + 16*i][k];
        }
        #pragma unroll
        for (int i = 0; i < 4; i++)
            #pragma unroll
            for (int j = 0; j < 4; j++)
                acc[i][j] += hv[i].x*wv[j].x + hv[i].y*wv[j].y
                           + hv[i].z*wv[j].z + hv[i].w*wv[j].w;
    }
    float bc[4], pwc[4], qwc[4];
    #pragma unroll
    for (int j = 0; j < 4; j++){
        int c = tx + 16*j;
        bc[j]  = t7b[c];
        pwc[j] = t5pw[D + c];
        qwc[j] = t5vw[D + c];
    }
    #pragma unroll
    for (int i = 0; i < 4; i++){
        float sp = 0.f, sq = 0.f;
        #pragma unroll
        for (int j = 0; j < 4; j++){
            float lv = fmaxf(acc[i][j] + bc[j], 0.f); // relu(h@t7w.T + b)
            sp = fmaf(lv, pwc[j], sp);
            sq = fmaf(lv, qwc[j], sq);
        }
        ppar[r0+i][tx] = sp;
        qpar[r0+i][tx] = sq;
    }
    __syncthreads();
    if (tid < 64){
        int t = rowBase + tid;
        float sp = 0.f, sq = 0.f;
        #pragma unroll
        for (int c = 0; c < 16; c++){ sp += ppar[tid][c]; sq += qpar[tid][c]; }
        float prob = PgQg[0] + sp + t5pb[0];
        out_logits[t] = prob * pw[0] + pb[0];
        float q = PgQg[1] + sq + t5vb[0];
        if (!reachable[t]) q = -1e20f;
        qbuf[t] = q;
    }
}

// ---------------- per-graph masked max -> value ----------------
__global__ void value_kernel(const float* __restrict__ qbuf, const float* __restrict__ vw,
                             const float* __restrict__ vb, float* __restrict__ out_value){
    __shared__ float part[256];
    int b = blockIdx.x, tid = threadIdx.x;
    float m = -INFINITY;
    for (int i = tid; i < NPG; i += 256) m = fmaxf(m, qbuf[b*NPG + i]);
    part[tid] = m;
    __syncthreads();
    for (int s = 128; s > 0; s >>= 1){
        if (tid < s) part[tid] = fmaxf(part[tid], part[tid+s]);
        __syncthreads();
    }
    if (tid == 0) out_value[b] = part[0]*vw[0] + vb[0];
}

extern "C" void kernel_launch(void* const* d_in, const int* in_sizes, int n_in,
                              void* d_out, int out_size, void* d_ws, size_t ws_size,
                              hipStream_t stream){
    const float* x          = (const float*)d_in[0];
    const int*   edge_index = (const int*)d_in[1];
    const int*   reachable  = (const int*)d_in[2];
    const float* Wl0 = (const float*)d_in[3];
    const float* Wr0 = (const float*)d_in[4];
    const float* att0= (const float*)d_in[5];
    const float* b0  = (const float*)d_in[6];
    const float* Wl  = (const float*)d_in[7];
    const float* Wr  = (const float*)d_in[8];
    const float* att = (const float*)d_in[9];
    const float* bb  = (const float*)d_in[10];
    const float* t6w = (const float*)d_in[11];
    const float* t6b = (const float*)d_in[12];
    const float* t7w = (const float*)d_in[13];
    const float* t7b = (const float*)d_in[14];
    const float* t5pw= (const float*)d_in[15];
    const float* t5pb= (const float*)d_in[16];
    const float* t5vw= (const float*)d_in[17];
    const float* t5vb= (const float*)d_in[18];
    const float* pw  = (const float*)d_in[19];
    const float* pb  = (const float*)d_in[20];
    const float* vw  = (const float*)d_in[21];
    const float* vb  = (const float*)d_in[22];

    int E = in_sizes[1] / 2;
    const int* esrc = edge_index;
    const int* edst = edge_index + E;

    char* ws = (char*)d_ws;
    float* h      = (float*)(ws);
    float* xl     = (float*)(ws + (size_t)T_NODES*D*4);
    float* xr     = (float*)(ws + (size_t)T_NODES*D*8);
    int*   counts = (int*)  (ws + (size_t)T_NODES*D*12);
    int*   indptr = (int*)((char*)counts + (size_t)(T_NODES+16)*4);
    int*   cursor = (int*)((char*)indptr + (size_t)(T_NODES+16)*4);
    int*   col    = (int*)((char*)cursor + (size_t)(T_NODES+16)*4);
    float* qbuf   = (float*)((char*)col + (size_t)(E+64)*4);
    float* muAcc  = (float*)((char*)qbuf + (size_t)T_NODES*4);

    // lin0 also zero-inits counts + muAcc (count/edge4 dispatches come later)
    lin0_kernel<<<T_NODES/32, 256, 0, stream>>>(x, Wl0, Wr0, xl, xr, counts, muAcc);
    count_kernel<<<(E+255)/256, 256, 0, stream>>>(edst, counts, E);
    scan_kernel<<<1, 1024, 0, stream>>>(counts, indptr, cursor, T_NODES);
    scatter_kernel<<<(E+255)/256, 256, 0, stream>>>(esrc, edst, cursor, col, E);

    edge_kernel<<<T_NODES/4, 256, 0, stream>>>(xl, xr, att0, b0, indptr, col, h,
                                               nullptr, E);
    for (int k = 0; k < 4; k++){
        lin_kernel<<<T_NODES/64, 256, 0, stream>>>(h, Wl + k*D*D, Wr + k*D*D, xl, xr);
        edge_kernel<<<T_NODES/4, 256, 0, stream>>>(xl, xr, att + k*D, bb + k*D, indptr, col, h,
                                                   (k == 3) ? muAcc : nullptr, E);
    }

    final_kernel<<<T_NODES/64, 256, 0, stream>>>(h, muAcc, t6w, t6b, t7w, t7b,
                                                 t5pw, t5pb, t5vw, t5vb, pw, pb,
                                                 reachable, (float*)d_out, qbuf);
    value_kernel<<<BGR, 256, 0, stream>>>(qbuf, vw, vb, (float*)d_out + T_NODES);
}